// Round 5
// baseline (1975.793 us; speedup 1.0000x reference)
//
#include <hip/hip_runtime.h>
#include <stdint.h>

#define B_DIM 8192
#define K_DIM 4096   // in_dim
#define N_DIM 4096   // out_dim

typedef unsigned short u16;
typedef float f4 __attribute__((ext_vector_type(4)));
typedef float f32x4 __attribute__((ext_vector_type(4)));
typedef __bf16 bf16x8 __attribute__((ext_vector_type(8)));
typedef unsigned short u16x8 __attribute__((ext_vector_type(8)));
typedef unsigned short u16x4 __attribute__((ext_vector_type(4)));

#define AS1(p) ((const __attribute__((address_space(1))) void*)(p))
#define AS3(p) ((__attribute__((address_space(3))) void*)(p))

__device__ __forceinline__ u16 f2bf(float f) {
  uint32_t u = __builtin_bit_cast(uint32_t, f);
  u += 0x7fffu + ((u >> 16) & 1u);   // RNE
  return (u16)(u >> 16);
}

__device__ __forceinline__ float wred(float v) {
#pragma unroll
  for (int o = 32; o > 0; o >>= 1) v += __shfl_xor(v, o);
  return v;
}

// ---------------- init: zero atomic accumulators ----------------
__global__ void k_init(float* __restrict__ stats) {
  for (int i = threadIdx.x; i < 8194; i += 256) stats[i] = 0.0f;
}

// ---------------- Wsum = bf16(W_slow + W_fast) ----------------
__global__ __launch_bounds__(256) void k_prep_w(const f4* __restrict__ wslow, const f4* __restrict__ wfast,
                                                u16x4* __restrict__ wo) {
  size_t stride = (size_t)gridDim.x * 256;
  size_t n4 = (size_t)N_DIM * K_DIM / 4;
  for (size_t i = (size_t)blockIdx.x * 256 + threadIdx.x; i < n4; i += stride) {
    f4 a = wslow[i], b = wfast[i];
    u16x4 o;
#pragma unroll
    for (int j = 0; j < 4; ++j) o[j] = f2bf(a[j] + b[j]);
    wo[i] = o;
  }
}

// ---------------- x -> bf16, accumulate sum(x^2) ----------------
__global__ __launch_bounds__(256) void k_prep_x(const f4* __restrict__ x, u16x4* __restrict__ xb,
                                                float* __restrict__ xsumsq) {
  __shared__ float red[4];
  size_t stride = (size_t)gridDim.x * 256;
  size_t n4 = (size_t)B_DIM * K_DIM / 4;
  float s = 0.f;
  for (size_t i = (size_t)blockIdx.x * 256 + threadIdx.x; i < n4; i += stride) {
    f4 v = x[i];
    u16x4 o;
#pragma unroll
    for (int j = 0; j < 4; ++j) { o[j] = f2bf(v[j]); s += v[j] * v[j]; }
    xb[i] = o;
  }
  s = wred(s);
  int lane = threadIdx.x & 63, wave = threadIdx.x >> 6;
  if (lane == 0) red[wave] = s;
  __syncthreads();
  if (threadIdx.x == 0) atomicAdd(xsumsq, red[0] + red[1] + red[2] + red[3]);
}

// ============ 256x256-tile pipelined bt-GEMM: C[M][N] = A[M][K] * B[N][K]^T ============
// bf16 in, f32 out. BK=64, 512 threads = 8 waves (2M x 4N), wave tile 128x64.
// Rotation (1-phase operand lookahead; each operand's last use precedes overwrite):
//   P0: read bB[t]          | Q0 = aA x bA   -> acc[0..3][0..1]   ; vmcnt(8) retires aB[t]
//   P1: read aB[t]  +stage aA[t+2]           | Q1 = aA x bB -> acc[0..3][2..3] ; vmcnt(8) retires aA[t+1]
//   P2: read aA[t+1]+stage B[t+2] (full)     | Q2 = aB x bA -> acc[4..7][0..1] ; vmcnt(8) retires B[t+1]
//   P3: read bA[t+1]+stage aB[t+2]           | Q3 = aB x bB -> acc[4..7][2..3]
// A stages quarter-granular (quarters align with aA/aB row sets); B full-tile.
// All staged-region readers lgkm-retired >=1 barrier before stage issue (audited).
// Every vmcnt-retired load is 4-5 phases old (~1000cy) -> never stalls on HBM.
__global__ __launch_bounds__(512, 2) void gemm8(const u16* __restrict__ A, const u16* __restrict__ Bm,
                                                float* __restrict__ C, int M, int N, int K) {
  __shared__ __align__(16) u16 As[32768];   // 2 bufs x 256 rows x 64 cols
  __shared__ __align__(16) u16 Bs[32768];

  const int tid = threadIdx.x, wave = tid >> 6, lane = tid & 63;
  const int li = lane & 15, hi = lane >> 4;
  const int wm = wave >> 2, wn = wave & 3;

  // bijective XCD swizzle (grid % 8 == 0 for both call sites)
  const int GX = N >> 8;
  const int nwg = GX * (M >> 8);
  int bid = blockIdx.y * GX + blockIdx.x;
  int swz = (bid & 7) * (nwg >> 3) + (bid >> 3);
  const int bx = swz % GX, by = swz / GX;
  const int m0 = by * 256, n0 = bx * 256;

  // per-lane staging source offsets (elements), swizzle-inverted:
  // LDS linear byte O holds tile byte T = O ^ (((O>>7)&7)<<4)
  int srcoff[2][2];
#pragma unroll
  for (int h = 0; h < 2; ++h)
#pragma unroll
    for (int q = 0; q < 2; ++q) {
      int O = h * 16384 + q * 8192 + wave * 1024 + lane * 16;
      int T = O ^ (((O >> 7) & 7) << 4);
      srcoff[h][q] = (T >> 7) * K + ((T & 127) >> 1);
    }

  const u16* Abase = A + (size_t)m0 * K;
  const u16* Bbase = Bm + (size_t)n0 * K;

// quarter stage: sub=0 -> rows {0-63,128-191} (aA rows); sub=1 -> rows {64-127,192-255} (aB rows)
#define STG_A2(buf, sub, kt) do { \
  __builtin_amdgcn_global_load_lds(AS1(Abase + (kt) + srcoff[0][sub]), AS3(&As[(buf)*16384 + (sub)*4096 + wave*512]), 16, 0, 0); \
  __builtin_amdgcn_global_load_lds(AS1(Abase + (kt) + srcoff[1][sub]), AS3(&As[(buf)*16384 + 8192 + (sub)*4096 + wave*512]), 16, 0, 0); \
} while (0)
#define STG_B2(buf, sub, kt) do { \
  __builtin_amdgcn_global_load_lds(AS1(Bbase + (kt) + srcoff[0][sub]), AS3(&Bs[(buf)*16384 + (sub)*4096 + wave*512]), 16, 0, 0); \
  __builtin_amdgcn_global_load_lds(AS1(Bbase + (kt) + srcoff[1][sub]), AS3(&Bs[(buf)*16384 + 8192 + (sub)*4096 + wave*512]), 16, 0, 0); \
} while (0)

  const int xa = (li & 7) << 3;                       // element-index XOR (byte bits[6:4])
  const int abase = (wm * 128 + li) * 64 + hi * 8;
  const int bbase = (wn * 64 + li) * 64 + hi * 8;
#define LDA_(dst, buf, m, ks) dst = *(const bf16x8*)&As[(buf)*16384 + (((abase + (m)*1024 + (ks)*32)) ^ xa)]
#define LDB_(dst, buf, n, ks) dst = *(const bf16x8*)&Bs[(buf)*16384 + (((bbase + (n)*1024 + (ks)*32)) ^ xa)]

  f32x4 acc[8][4] = {};
  bf16x8 aA[4][2], aB[4][2], bA[2][2], bB[2][2];
  const int NT = K >> 6;

  // prologue: tile0 {aA,B,aB}, tile1 {aA,B,aB}; wait tile0 (vmcnt(8)); pre-read aA[0], bA[0]
  STG_A2(0, 0, 0); STG_B2(0, 0, 0); STG_B2(0, 1, 0); STG_A2(0, 1, 0);
  STG_A2(1, 0, 64); STG_B2(1, 0, 64); STG_B2(1, 1, 64); STG_A2(1, 1, 64);
  asm volatile("s_waitcnt vmcnt(8)" ::: "memory");
  __builtin_amdgcn_s_barrier();
#pragma unroll
  for (int m = 0; m < 4; ++m) { LDA_(aA[m][0], 0, m, 0); LDA_(aA[m][1], 0, m, 1); }
  LDB_(bA[0][0], 0, 0, 0); LDB_(bA[0][1], 0, 0, 1);
  LDB_(bA[1][0], 0, 1, 0); LDB_(bA[1][1], 0, 1, 1);

#define MFMA_Q(MLO, NLO, AOP, BOP)                                                  \
    __builtin_amdgcn_sched_barrier(0);                                              \
    __builtin_amdgcn_s_setprio(1);                                                  \
    _Pragma("unroll")                                                               \
    for (int ks = 0; ks < 2; ++ks)                                                  \
      _Pragma("unroll")                                                             \
      for (int m = 0; m < 4; ++m)                                                   \
        _Pragma("unroll")                                                           \
        for (int n = 0; n < 2; ++n)                                                 \
          acc[m + MLO][n + NLO] = __builtin_amdgcn_mfma_f32_16x16x32_bf16(          \
              AOP[m][ks], BOP[n][ks], acc[m + MLO][n + NLO], 0, 0, 0);              \
    __builtin_amdgcn_sched_barrier(0);                                              \
    __builtin_amdgcn_s_setprio(0);

#define RD_BB(X_) \
    LDB_(bB[0][0], X_, 2, 0); LDB_(bB[0][1], X_, 2, 1); \
    LDB_(bB[1][0], X_, 3, 0); LDB_(bB[1][1], X_, 3, 1);
#define RD_AB(X_) \
    _Pragma("unroll") \
    for (int m = 0; m < 4; ++m) { LDA_(aB[m][0], X_, m + 4, 0); LDA_(aB[m][1], X_, m + 4, 1); }
#define RD_AA_N(X_) \
    _Pragma("unroll") \
    for (int m = 0; m < 4; ++m) { LDA_(aA[m][0], (X_) ^ 1, m, 0); LDA_(aA[m][1], (X_) ^ 1, m, 1); }
#define RD_BA_N(X_) \
    LDB_(bA[0][0], (X_) ^ 1, 0, 0); LDB_(bA[0][1], (X_) ^ 1, 0, 1); \
    LDB_(bA[1][0], (X_) ^ 1, 1, 0); LDB_(bA[1][1], (X_) ^ 1, 1, 1);
#define BAR __builtin_amdgcn_s_barrier()
#define LGKM(n) asm volatile("s_waitcnt lgkmcnt(" #n ")" ::: "memory")
#define VMC(n)  asm volatile("s_waitcnt vmcnt(" #n ")" ::: "memory")

#define TILE_BODY(X_, t_) do {                                                      \
    const int kt2 = ((t_) + 2) << 6;                                                \
    /* P0 */ RD_BB(X_) BAR; LGKM(4); MFMA_Q(0, 0, aA, bA) VMC(8); BAR;              \
    /* P1 */ RD_AB(X_) STG_A2(X_, 0, kt2);                                          \
             BAR; LGKM(8); MFMA_Q(0, 2, aA, bB) VMC(8); BAR;                        \
    /* P2 */ RD_AA_N(X_) STG_B2(X_, 0, kt2); STG_B2(X_, 1, kt2);                    \
             BAR; LGKM(8); MFMA_Q(4, 0, aB, bA) VMC(8); BAR;                        \
    /* P3 */ RD_BA_N(X_) STG_A2(X_, 1, kt2);                                        \
             BAR; MFMA_Q(4, 2, aB, bB) BAR;                                         \
  } while (0)

#define TILE_TAIL1(X_) do {                                                         \
    /* P0 */ RD_BB(X_) BAR; LGKM(4); MFMA_Q(0, 0, aA, bA) VMC(8); BAR;              \
    /* P1 */ RD_AB(X_) BAR; LGKM(8); MFMA_Q(0, 2, aA, bB) VMC(6); BAR;              \
    /* P2 */ RD_AA_N(X_) BAR; LGKM(8); MFMA_Q(4, 0, aB, bA) VMC(2); BAR;            \
    /* P3 */ RD_BA_N(X_) BAR; MFMA_Q(4, 2, aB, bB) BAR;                             \
  } while (0)

#define TILE_TAIL2(X_) do {                                                         \
    /* P0 */ RD_BB(X_) BAR; LGKM(4); MFMA_Q(0, 0, aA, bA) VMC(0); BAR;              \
    /* P1 */ RD_AB(X_) BAR; LGKM(8); MFMA_Q(0, 2, aA, bB) BAR;                      \
    /* P2 */ BAR; LGKM(0); MFMA_Q(4, 0, aB, bA) BAR;                                \
    /* P3 */ BAR; MFMA_Q(4, 2, aB, bB) BAR;                                         \
  } while (0)

  for (int t = 0; t < NT - 2; t += 2) {
    TILE_BODY(0, t);
    TILE_BODY(1, t + 1);
  }
  TILE_TAIL1(0);
  TILE_TAIL2(1);

  // epilogue: C/D layout col = lane&15, row = (lane>>4)*4 + j
  float* Cp = C + (size_t)(m0 + wm * 128 + hi * 4) * N + n0 + wn * 64 + li;
#pragma unroll
  for (int m = 0; m < 8; ++m)
#pragma unroll
    for (int n = 0; n < 4; ++n)
#pragma unroll
      for (int j = 0; j < 4; ++j)
        Cp[(size_t)(m * 16 + j) * N + n * 16] = acc[m][n][j];
#undef TILE_BODY
#undef TILE_TAIL1
#undef TILE_TAIL2
#undef MFMA_Q
#undef RD_BB
#undef RD_AB
#undef RD_AA_N
#undef RD_BA_N
#undef BAR
#undef LGKM
#undef VMC
#undef STG_A2
#undef STG_B2
#undef LDA_
#undef LDB_
}

// ---------------- column stats over batch ----------------
__global__ __launch_bounds__(256) void k_colstats(const float* __restrict__ pre,
                                                  float* __restrict__ colsum, float* __restrict__ colsumsq) {
  int col = blockIdx.x * 256 + threadIdx.x;
  int r0 = blockIdx.y * 128;
  const float* p = pre + (size_t)r0 * N_DIM + col;
  float s = 0.f, q = 0.f;
#pragma unroll 4
  for (int i = 0; i < 128; ++i) {
    float v = p[(size_t)i * N_DIM];
    s += v; q += v * v;
  }
  atomicAdd(&colsum[col], s);
  atomicAdd(&colsumsq[col], q);
}

// ---------------- plasticity MLP per column ----------------
__global__ __launch_bounds__(256) void k_mlp(const float* __restrict__ colsum, const float* __restrict__ colsumsq,
                                             const float* __restrict__ w1, const float* __restrict__ b1,
                                             const float* __restrict__ w2, const float* __restrict__ b2,
                                             const float* __restrict__ gp, float* __restrict__ eff,
                                             float* __restrict__ effsum) {
  __shared__ float red[4];
  int c = blockIdx.x * 256 + threadIdx.x;
  float mean = colsum[c] * (1.0f / B_DIM);
  float var = (colsumsq[c] - (float)B_DIM * mean * mean) * (1.0f / (B_DIM - 1));
  float sd = sqrtf(fmaxf(var, 0.f)) + 1e-6f;
  float acc = b2[0];
#pragma unroll
  for (int i = 0; i < 16; ++i) {
    float h = tanhf(mean * w1[2 * i] + sd * w1[2 * i + 1] + b1[i]);
    acc += h * w2[i];
  }
  float p = 1.0f / (1.0f + expf(-acc));
  float e = gp[0] * p;          // * (1 - PRED_ERR), PRED_ERR = 0
  eff[c] = e;
  float s = wred(e);
  int lane = threadIdx.x & 63, wave = threadIdx.x >> 6;
  if (lane == 0) red[wave] = s;
  __syncthreads();
  if (threadIdx.x == 0) atomicAdd(effsum, red[0] + red[1] + red[2] + red[3]);
}

// ---------------- row LayerNorm + 5*tanh(/5); in-place over pre_act; also bf16 copy ----------------
__global__ __launch_bounds__(256) void k_ln(const float* __restrict__ pre, const float* __restrict__ gamma,
                                            const float* __restrict__ beta, float* __restrict__ outF,
                                            u16* __restrict__ outB) {
  __shared__ float row[N_DIM];
  __shared__ float red[2][4];
  int t = threadIdx.x, lane = t & 63, wave = t >> 6;
  const float* p = pre + (size_t)blockIdx.x * N_DIM;
  float s = 0.f;
#pragma unroll
  for (int q = 0; q < 4; ++q) {
    int c = (q * 256 + t) * 4;
    f4 v = *(const f4*)&p[c];
    *(f4*)&row[c] = v;
    s += v[0] + v[1] + v[2] + v[3];
  }
  s = wred(s);
  if (lane == 0) red[0][wave] = s;
  __syncthreads();
  float mean = (red[0][0] + red[0][1] + red[0][2] + red[0][3]) * (1.0f / N_DIM);
  float vs = 0.f;
#pragma unroll
  for (int q = 0; q < 4; ++q) {
    int c = (q * 256 + t) * 4;
    f4 v = *(const f4*)&row[c];
#pragma unroll
    for (int j = 0; j < 4; ++j) { float d = v[j] - mean; vs += d * d; }
  }
  vs = wred(vs);
  if (lane == 0) red[1][wave] = vs;
  __syncthreads();
  float var = (red[1][0] + red[1][1] + red[1][2] + red[1][3]) * (1.0f / N_DIM);
  float rstd = rsqrtf(var + 1e-5f);
  float* o = outF + (size_t)blockIdx.x * N_DIM;
  u16* ob = outB + (size_t)blockIdx.x * N_DIM;
#pragma unroll
  for (int q = 0; q < 4; ++q) {
    int c = (q * 256 + t) * 4;
    f4 v = *(const f4*)&row[c];
    f4 g = *(const f4*)&gamma[c];
    f4 be = *(const f4*)&beta[c];
    f4 r;
    u16x4 rb;
#pragma unroll
    for (int j = 0; j < 4; ++j) {
      float ln = (v[j] - mean) * rstd * g[j] + be[j];
      float ov = 5.0f * tanhf(ln * 0.2f);
      r[j] = ov; rb[j] = f2bf(ov);
    }
    *(f4*)&o[c] = r;
    *(u16x4*)&ob[c] = rb;
  }
}

// ---------------- bf16 64x64 tile transpose: dst[c][r] = src[r][c] ----------------
__global__ __launch_bounds__(256) void k_transpose(const u16* __restrict__ src, u16* __restrict__ dst,
                                                   int R, int C) {
  __shared__ u16 tile[64][65];
  int tc = blockIdx.x, tr = blockIdx.y;
  int t = threadIdx.x;
#pragma unroll
  for (int q = 0; q < 2; ++q) {
    int idx = q * 256 + t;
    int row = idx >> 3, cg = idx & 7;
    u16x8 v = *(const u16x8*)&src[(size_t)(tr * 64 + row) * C + tc * 64 + cg * 8];
#pragma unroll
    for (int j = 0; j < 8; ++j) tile[row][cg * 8 + j] = v[j];
  }
  __syncthreads();
#pragma unroll
  for (int q = 0; q < 2; ++q) {
    int idx = q * 256 + t;
    int row = idx >> 3, cg = idx & 7;
    u16x8 v;
#pragma unroll
    for (int j = 0; j < 8; ++j) v[j] = tile[cg * 8 + j][row];
    *(u16x8*)&dst[(size_t)(tc * 64 + row) * R + tr * 64 + cg * 8] = v;
  }
}

// ---------------- Hebbian W_fast update (in-place over corr region of d_out) ----------------
__global__ __launch_bounds__(256) void k_update(const float* __restrict__ corr, const float* __restrict__ wf,
                                                const float* __restrict__ eff, const float* __restrict__ sc,
                                                float* __restrict__ out_wf) {
  float xn = sc[0] * (1.0f / B_DIM) + 1e-6f;
  float inv = 1.0f / ((float)B_DIM * xn);
  bool on = (sc[1] * (1.0f / N_DIM)) > 0.001f;
  size_t i = ((size_t)blockIdx.x * 256 + threadIdx.x) * 4;
  int n = (int)(i >> 12);
  float lr = eff[n] * 0.015f;
  f4 c4 = *(const f4*)&corr[i];
  f4 w4 = *(const f4*)&wf[i];
  f4 r;
#pragma unroll
  for (int j = 0; j < 4; ++j) {
    float delta = fminf(fmaxf(c4[j] * inv - 0.2f * w4[j], -0.05f), 0.05f);
    r[j] = on ? (w4[j] + delta * lr) * 0.999f : w4[j];
  }
  *(f4*)&out_wf[i] = r;
}

extern "C" void kernel_launch(void* const* d_in, const int* in_sizes, int n_in,
                              void* d_out, int out_size, void* d_ws, size_t ws_size,
                              hipStream_t stream) {
  const float* x      = (const float*)d_in[0];
  const float* W_slow = (const float*)d_in[1];
  const float* W_fast = (const float*)d_in[2];
  const float* gamma  = (const float*)d_in[3];
  const float* beta   = (const float*)d_in[4];
  const float* w1     = (const float*)d_in[5];
  const float* b1     = (const float*)d_in[6];
  const float* w2     = (const float*)d_in[7];
  const float* b2     = (const float*)d_in[8];
  const float* gp     = (const float*)d_in[9];

  float* outF = (float*)d_out;                         // [8192][4096] out
  float* outW = (float*)d_out + (size_t)B_DIM * N_DIM; // [4096][4096] new_W_fast

  uint8_t* ws = (uint8_t*)d_ws;
  u16*  x_bf   = (u16*)(ws + 0);                        // 64MB
  u16*  outT   = (u16*)(ws + 0);                        // alias after x-transpose
  u16*  wsum   = (u16*)(ws + 67108864);                 // 32MB
  u16*  out_bf = (u16*)(ws + 67108864);                 // alias after GEMM1 (64MB)
  u16*  xT     = (u16*)(ws + 134217728);                // 64MB
  float* stats = (float*)(ws + 201326592);
  float* colsum   = stats;
  float* colsumsq = stats + 4096;
  float* xsumsq   = stats + 8192;
  float* effsum   = stats + 8193;
  float* eff      = stats + 8448;

  k_init<<<1, 256, 0, stream>>>(stats);
  k_prep_w<<<2048, 256, 0, stream>>>((const f4*)W_slow, (const f4*)W_fast, (u16x4*)wsum);
  k_prep_x<<<2048, 256, 0, stream>>>((const f4*)x, (u16x4*)x_bf, xsumsq);
  gemm8<<<dim3(N_DIM / 256, B_DIM / 256), 512, 0, stream>>>(x_bf, wsum, outF, B_DIM, N_DIM, K_DIM);
  k_colstats<<<dim3(N_DIM / 256, B_DIM / 128), 256, 0, stream>>>(outF, colsum, colsumsq);
  k_mlp<<<N_DIM / 256, 256, 0, stream>>>(colsum, colsumsq, w1, b1, w2, b2, gp, eff, effsum);
  k_ln<<<B_DIM, 256, 0, stream>>>(outF, gamma, beta, outF, out_bf);
  k_transpose<<<dim3(K_DIM / 64, B_DIM / 64), 256, 0, stream>>>(x_bf, xT, B_DIM, K_DIM);
  k_transpose<<<dim3(N_DIM / 64, B_DIM / 64), 256, 0, stream>>>(out_bf, outT, B_DIM, N_DIM);
  gemm8<<<dim3(K_DIM / 256, N_DIM / 256), 512, 0, stream>>>(outT, xT, outW, N_DIM, K_DIM, B_DIM);
  k_update<<<(N_DIM * K_DIM / 4) / 256, 256, 0, stream>>>(outW, W_fast, eff, xsumsq, outW);
}

// Round 6
// 770.975 us; speedup vs baseline: 2.5627x; 2.5627x over previous
//
#include <hip/hip_runtime.h>
#include <stdint.h>

#define B_DIM 8192
#define K_DIM 4096   // in_dim
#define N_DIM 4096   // out_dim

typedef unsigned short u16;
typedef float f4 __attribute__((ext_vector_type(4)));
typedef float f32x4 __attribute__((ext_vector_type(4)));
typedef __bf16 bf16x8 __attribute__((ext_vector_type(8)));
typedef unsigned short u16x8 __attribute__((ext_vector_type(8)));
typedef unsigned short u16x4 __attribute__((ext_vector_type(4)));

#define AS1(p) ((const __attribute__((address_space(1))) void*)(p))
#define AS3(p) ((__attribute__((address_space(3))) void*)(p))

__device__ __forceinline__ u16 f2bf(float f) {
  uint32_t u = __builtin_bit_cast(uint32_t, f);
  u += 0x7fffu + ((u >> 16) & 1u);   // RNE
  return (u16)(u >> 16);
}

__device__ __forceinline__ float wred(float v) {
#pragma unroll
  for (int o = 32; o > 0; o >>= 1) v += __shfl_xor(v, o);
  return v;
}

// ---------------- init: zero atomic accumulators ----------------
__global__ void k_init(float* __restrict__ stats) {
  for (int i = threadIdx.x; i < 8194; i += 256) stats[i] = 0.0f;
}

// ---------------- Wsum = bf16(W_slow + W_fast) ----------------
__global__ __launch_bounds__(256) void k_prep_w(const f4* __restrict__ wslow, const f4* __restrict__ wfast,
                                                u16x4* __restrict__ wo) {
  size_t stride = (size_t)gridDim.x * 256;
  size_t n4 = (size_t)N_DIM * K_DIM / 4;
  for (size_t i = (size_t)blockIdx.x * 256 + threadIdx.x; i < n4; i += stride) {
    f4 a = wslow[i], b = wfast[i];
    u16x4 o;
#pragma unroll
    for (int j = 0; j < 4; ++j) o[j] = f2bf(a[j] + b[j]);
    wo[i] = o;
  }
}

// ---------------- x -> bf16, accumulate sum(x^2) ----------------
__global__ __launch_bounds__(256) void k_prep_x(const f4* __restrict__ x, u16x4* __restrict__ xb,
                                                float* __restrict__ xsumsq) {
  __shared__ float red[4];
  size_t stride = (size_t)gridDim.x * 256;
  size_t n4 = (size_t)B_DIM * K_DIM / 4;
  float s = 0.f;
  for (size_t i = (size_t)blockIdx.x * 256 + threadIdx.x; i < n4; i += stride) {
    f4 v = x[i];
    u16x4 o;
#pragma unroll
    for (int j = 0; j < 4; ++j) { o[j] = f2bf(v[j]); s += v[j] * v[j]; }
    xb[i] = o;
  }
  s = wred(s);
  int lane = threadIdx.x & 63, wave = threadIdx.x >> 6;
  if (lane == 0) red[wave] = s;
  __syncthreads();
  if (threadIdx.x == 0) atomicAdd(xsumsq, red[0] + red[1] + red[2] + red[3]);
}

// ============ 256x256-tile pipelined bt-GEMM: C[M][N] = A[M][K] * B[N][K]^T ============
// bf16 in, f32 out. BK=64, 512 threads = 8 waves (2M x 4N), wave tile 128x64.
// R2 structure + minimal B-lookahead (balanced 8/4/8/4 ds_reads per phase):
//   P0: read a03(t) [8] + stage A(t+1).q0 | Q0 = a03 x b01      (b01 read prev P3)
//   P1: read b23(t) [4] + stage A(t+1).q1 | Q1 = a03 x b23 ; VMC(8)
//   P2: read a47(t) [8] + stage B(t+2).c0 | Q2 = a47 x b23 ; VMC(6)
//   P3: read b01(t+1)[4]-> alt bank + stage B(t+2).c1 | Q3 = a47 x b01(old bank),
//       gate lgkmcnt(4) leaves the lookahead reads in flight ; VMC(6)
// Only b01 double-banked (2x16 regs) crosses MFMA clusters -> 80 persistent operand
// VGPRs, fits the 128-arch-VGPR cap (256 unified/wave at 2 waves/SIMD). [R5 lesson]
// A staged quarter-wise (q0 = rows{0-63,128-191} = a03 rows; q1 = a47 rows);
// B staged as 2 arbitrary chunks, both land before first read (vmcnt ledger audited).
__global__ __launch_bounds__(512, 2) void gemm8(const u16* __restrict__ A, const u16* __restrict__ Bm,
                                                float* __restrict__ C, int M, int N, int K) {
  __shared__ __align__(16) u16 As[32768];   // 2 bufs x 256 rows x 64 cols
  __shared__ __align__(16) u16 Bs[32768];

  const int tid = threadIdx.x, wave = tid >> 6, lane = tid & 63;
  const int li = lane & 15, hi = lane >> 4;
  const int wm = wave >> 2, wn = wave & 3;

  // bijective XCD swizzle (grid % 8 == 0 for both call sites)
  const int GX = N >> 8;
  const int nwg = GX * (M >> 8);
  int bid = blockIdx.y * GX + blockIdx.x;
  int swz = (bid & 7) * (nwg >> 3) + (bid >> 3);
  const int bx = swz % GX, by = swz / GX;
  const int m0 = by * 256, n0 = bx * 256;

  // per-lane staging source offsets (elements), swizzle-inverted:
  // LDS linear byte O holds tile byte T = O ^ (((O>>7)&7)<<4)
  int srcoff[2][2];
#pragma unroll
  for (int g = 0; g < 2; ++g)
#pragma unroll
    for (int s = 0; s < 2; ++s) {
      int O = g * 16384 + s * 8192 + wave * 1024 + lane * 16;
      int T = O ^ (((O >> 7) & 7) << 4);
      srcoff[g][s] = (T >> 7) * K + ((T & 127) >> 1);
    }

  const u16* Abase = A + (size_t)m0 * K;
  const u16* Bbase = Bm + (size_t)n0 * K;

// quarter stage for A: sub=0 -> rows {0-63,128-191} (a03 rows); sub=1 -> {64-127,192-255} (a47)
#define STG_AQ(buf, sub, kt) do { \
  __builtin_amdgcn_global_load_lds(AS1(Abase + (kt) + srcoff[0][sub]), AS3(&As[(buf)*16384 + (sub)*4096 + wave*512]), 16, 0, 0); \
  __builtin_amdgcn_global_load_lds(AS1(Abase + (kt) + srcoff[1][sub]), AS3(&As[(buf)*16384 + 8192 + (sub)*4096 + wave*512]), 16, 0, 0); \
} while (0)
#define STG_BC(buf, c, kt) do { \
  __builtin_amdgcn_global_load_lds(AS1(Bbase + (kt) + srcoff[0][c]), AS3(&Bs[(buf)*16384 + (c)*4096 + wave*512]), 16, 0, 0); \
  __builtin_amdgcn_global_load_lds(AS1(Bbase + (kt) + srcoff[1][c]), AS3(&Bs[(buf)*16384 + 8192 + (c)*4096 + wave*512]), 16, 0, 0); \
} while (0)

  const int xa = (li & 7) << 3;                       // element-index XOR (byte bits[6:4])
  const int abase = (wm * 128 + li) * 64 + hi * 8;
  const int bbase = (wn * 64 + li) * 64 + hi * 8;
#define LDA_(dst, buf, m, ks) dst = *(const bf16x8*)&As[(buf)*16384 + (((abase + (m)*1024 + (ks)*32)) ^ xa)]
#define LDB_(dst, buf, n, ks) dst = *(const bf16x8*)&Bs[(buf)*16384 + (((bbase + (n)*1024 + (ks)*32)) ^ xa)]

  f32x4 acc[8][4] = {};
  bf16x8 a[4][2], b23[2][2], b01a[2][2], b01b[2][2];
  const int NT = K >> 6;

  // prologue: stage A(0),B(0) -> buf0, B(1) -> buf1; retire tile0; pre-read b01(0) -> b01a
  STG_AQ(0, 0, 0); STG_AQ(0, 1, 0); STG_BC(0, 0, 0); STG_BC(0, 1, 0);
  STG_BC(1, 0, 64); STG_BC(1, 1, 64);
  asm volatile("s_waitcnt vmcnt(4)" ::: "memory");
  __builtin_amdgcn_s_barrier();
  LDB_(b01a[0][0], 0, 0, 0); LDB_(b01a[0][1], 0, 0, 1);
  LDB_(b01a[1][0], 0, 1, 0); LDB_(b01a[1][1], 0, 1, 1);

#define RD_A03(X_) _Pragma("unroll") \
    for (int m = 0; m < 4; ++m) { LDA_(a[m][0], X_, m, 0); LDA_(a[m][1], X_, m, 1); }
#define RD_A47(X_) _Pragma("unroll") \
    for (int m = 0; m < 4; ++m) { LDA_(a[m][0], X_, m + 4, 0); LDA_(a[m][1], X_, m + 4, 1); }
#define RD_B23(X_) \
    LDB_(b23[0][0], X_, 2, 0); LDB_(b23[0][1], X_, 2, 1); \
    LDB_(b23[1][0], X_, 3, 0); LDB_(b23[1][1], X_, 3, 1);
#define RD_B01(X_, BK_) \
    LDB_(BK_[0][0], X_, 0, 0); LDB_(BK_[0][1], X_, 0, 1); \
    LDB_(BK_[1][0], X_, 1, 0); LDB_(BK_[1][1], X_, 1, 1);
#define BAR __builtin_amdgcn_s_barrier()
#define LGKM(n) asm volatile("s_waitcnt lgkmcnt(" #n ")" ::: "memory")
#define VMC(n)  asm volatile("s_waitcnt vmcnt(" #n ")" ::: "memory")
#define SB __builtin_amdgcn_sched_barrier(0)

#define MFMA_Q(MLO, NLO, BOP)                                                       \
    __builtin_amdgcn_s_setprio(1);                                                  \
    _Pragma("unroll")                                                               \
    for (int ks = 0; ks < 2; ++ks)                                                  \
      _Pragma("unroll")                                                             \
      for (int m = 0; m < 4; ++m)                                                   \
        _Pragma("unroll")                                                           \
        for (int n = 0; n < 2; ++n)                                                 \
          acc[m + MLO][n + NLO] = __builtin_amdgcn_mfma_f32_16x16x32_bf16(          \
              a[m][ks], BOP[n][ks], acc[m + MLO][n + NLO], 0, 0, 0);                \
    __builtin_amdgcn_s_setprio(0);

// steady-state tile: CURB = current b01 bank, NXTB = bank being filled for t+1
#define TILE_BODY(X_, t_, CURB, NXTB) do {                                          \
    const int kt1 = ((t_) + 1) << 6, kt2 = ((t_) + 2) << 6;                         \
    /* P0 */ RD_A03(X_) STG_AQ((X_) ^ 1, 0, kt1);                                   \
             BAR; LGKM(0); SB; MFMA_Q(0, 0, CURB) BAR;                              \
    /* P1 */ RD_B23(X_) STG_AQ((X_) ^ 1, 1, kt1);                                   \
             BAR; LGKM(0); SB; MFMA_Q(0, 2, b23) VMC(8); BAR;                       \
    /* P2 */ RD_A47(X_) STG_BC(X_, 0, kt2);                                         \
             BAR; LGKM(0); SB; MFMA_Q(4, 2, b23) VMC(6); BAR;                       \
    /* P3 */ RD_B01((X_) ^ 1, NXTB) STG_BC(X_, 1, kt2);                             \
             BAR; LGKM(4); SB; MFMA_Q(4, 0, CURB) VMC(6); BAR;                      \
  } while (0)

// tail tile NT-2 (even, buf0, uses b01a, fills b01b); stages A(NT-1) only
#define TILE_TAILA(t_) do {                                                         \
    const int kt1 = ((t_) + 1) << 6;                                                \
    /* P0 */ RD_A03(0) STG_AQ(1, 0, kt1); BAR; LGKM(0); SB; MFMA_Q(0, 0, b01a) BAR; \
    /* P1 */ RD_B23(0) STG_AQ(1, 1, kt1); BAR; LGKM(0); SB; MFMA_Q(0, 2, b23) VMC(8); BAR; \
    /* P2 */ RD_A47(0) BAR; LGKM(0); SB; MFMA_Q(4, 2, b23) VMC(4); BAR;             \
    /* P3 */ RD_B01(1, b01b) BAR; LGKM(4); SB; MFMA_Q(4, 0, b01a) VMC(2); BAR;      \
  } while (0)

// tail tile NT-1 (odd, buf1, uses b01b); no staging, no lookahead
#define TILE_TAILB() do {                                                           \
    /* P0 */ RD_A03(1) BAR; LGKM(0); SB; MFMA_Q(0, 0, b01b) BAR;                    \
    /* P1 */ RD_B23(1) BAR; LGKM(0); SB; MFMA_Q(0, 2, b23) VMC(0); BAR;             \
    /* P2 */ RD_A47(1) BAR; LGKM(0); SB; MFMA_Q(4, 2, b23) BAR;                     \
    /* P3 */ BAR; MFMA_Q(4, 0, b01b) BAR;                                           \
  } while (0)

  for (int t = 0; t + 2 < NT; t += 2) {
    TILE_BODY(0, t, b01a, b01b);
    TILE_BODY(1, t + 1, b01b, b01a);
  }
  TILE_TAILA(NT - 2);
  TILE_TAILB();

  // epilogue: C/D layout col = lane&15, row = (lane>>4)*4 + j
  float* Cp = C + (size_t)(m0 + wm * 128 + hi * 4) * N + n0 + wn * 64 + li;
#pragma unroll
  for (int m = 0; m < 8; ++m)
#pragma unroll
    for (int n = 0; n < 4; ++n)
#pragma unroll
      for (int j = 0; j < 4; ++j)
        Cp[(size_t)(m * 16 + j) * N + n * 16] = acc[m][n][j];
#undef TILE_BODY
#undef TILE_TAILA
#undef TILE_TAILB
#undef MFMA_Q
#undef RD_A03
#undef RD_A47
#undef RD_B23
#undef RD_B01
#undef BAR
#undef LGKM
#undef VMC
#undef SB
#undef STG_AQ
#undef STG_BC
#undef LDA_
#undef LDB_
}

// ---------------- column stats over batch ----------------
__global__ __launch_bounds__(256) void k_colstats(const float* __restrict__ pre,
                                                  float* __restrict__ colsum, float* __restrict__ colsumsq) {
  int col = blockIdx.x * 256 + threadIdx.x;
  int r0 = blockIdx.y * 128;
  const float* p = pre + (size_t)r0 * N_DIM + col;
  float s = 0.f, q = 0.f;
#pragma unroll 4
  for (int i = 0; i < 128; ++i) {
    float v = p[(size_t)i * N_DIM];
    s += v; q += v * v;
  }
  atomicAdd(&colsum[col], s);
  atomicAdd(&colsumsq[col], q);
}

// ---------------- plasticity MLP per column ----------------
__global__ __launch_bounds__(256) void k_mlp(const float* __restrict__ colsum, const float* __restrict__ colsumsq,
                                             const float* __restrict__ w1, const float* __restrict__ b1,
                                             const float* __restrict__ w2, const float* __restrict__ b2,
                                             const float* __restrict__ gp, float* __restrict__ eff,
                                             float* __restrict__ effsum) {
  __shared__ float red[4];
  int c = blockIdx.x * 256 + threadIdx.x;
  float mean = colsum[c] * (1.0f / B_DIM);
  float var = (colsumsq[c] - (float)B_DIM * mean * mean) * (1.0f / (B_DIM - 1));
  float sd = sqrtf(fmaxf(var, 0.f)) + 1e-6f;
  float acc = b2[0];
#pragma unroll
  for (int i = 0; i < 16; ++i) {
    float h = tanhf(mean * w1[2 * i] + sd * w1[2 * i + 1] + b1[i]);
    acc += h * w2[i];
  }
  float p = 1.0f / (1.0f + expf(-acc));
  float e = gp[0] * p;          // * (1 - PRED_ERR), PRED_ERR = 0
  eff[c] = e;
  float s = wred(e);
  int lane = threadIdx.x & 63, wave = threadIdx.x >> 6;
  if (lane == 0) red[wave] = s;
  __syncthreads();
  if (threadIdx.x == 0) atomicAdd(effsum, red[0] + red[1] + red[2] + red[3]);
}

// ---------------- row LayerNorm + 5*tanh(/5); in-place over pre_act; also bf16 copy ----------------
__global__ __launch_bounds__(256) void k_ln(const float* __restrict__ pre, const float* __restrict__ gamma,
                                            const float* __restrict__ beta, float* __restrict__ outF,
                                            u16* __restrict__ outB) {
  __shared__ float row[N_DIM];
  __shared__ float red[2][4];
  int t = threadIdx.x, lane = t & 63, wave = t >> 6;
  const float* p = pre + (size_t)blockIdx.x * N_DIM;
  float s = 0.f;
#pragma unroll
  for (int q = 0; q < 4; ++q) {
    int c = (q * 256 + t) * 4;
    f4 v = *(const f4*)&p[c];
    *(f4*)&row[c] = v;
    s += v[0] + v[1] + v[2] + v[3];
  }
  s = wred(s);
  if (lane == 0) red[0][wave] = s;
  __syncthreads();
  float mean = (red[0][0] + red[0][1] + red[0][2] + red[0][3]) * (1.0f / N_DIM);
  float vs = 0.f;
#pragma unroll
  for (int q = 0; q < 4; ++q) {
    int c = (q * 256 + t) * 4;
    f4 v = *(const f4*)&row[c];
#pragma unroll
    for (int j = 0; j < 4; ++j) { float d = v[j] - mean; vs += d * d; }
  }
  vs = wred(vs);
  if (lane == 0) red[1][wave] = vs;
  __syncthreads();
  float var = (red[1][0] + red[1][1] + red[1][2] + red[1][3]) * (1.0f / N_DIM);
  float rstd = rsqrtf(var + 1e-5f);
  float* o = outF + (size_t)blockIdx.x * N_DIM;
  u16* ob = outB + (size_t)blockIdx.x * N_DIM;
#pragma unroll
  for (int q = 0; q < 4; ++q) {
    int c = (q * 256 + t) * 4;
    f4 v = *(const f4*)&row[c];
    f4 g = *(const f4*)&gamma[c];
    f4 be = *(const f4*)&beta[c];
    f4 r;
    u16x4 rb;
#pragma unroll
    for (int j = 0; j < 4; ++j) {
      float ln = (v[j] - mean) * rstd * g[j] + be[j];
      float ov = 5.0f * tanhf(ln * 0.2f);
      r[j] = ov; rb[j] = f2bf(ov);
    }
    *(f4*)&o[c] = r;
    *(u16x4*)&ob[c] = rb;
  }
}

// ---------------- bf16 64x64 tile transpose: dst[c][r] = src[r][c] ----------------
__global__ __launch_bounds__(256) void k_transpose(const u16* __restrict__ src, u16* __restrict__ dst,
                                                   int R, int C) {
  __shared__ u16 tile[64][65];
  int tc = blockIdx.x, tr = blockIdx.y;
  int t = threadIdx.x;
#pragma unroll
  for (int q = 0; q < 2; ++q) {
    int idx = q * 256 + t;
    int row = idx >> 3, cg = idx & 7;
    u16x8 v = *(const u16x8*)&src[(size_t)(tr * 64 + row) * C + tc * 64 + cg * 8];
#pragma unroll
    for (int j = 0; j < 8; ++j) tile[row][cg * 8 + j] = v[j];
  }
  __syncthreads();
#pragma unroll
  for (int q = 0; q < 2; ++q) {
    int idx = q * 256 + t;
    int row = idx >> 3, cg = idx & 7;
    u16x8 v;
#pragma unroll
    for (int j = 0; j < 8; ++j) v[j] = tile[cg * 8 + j][row];
    *(u16x8*)&dst[(size_t)(tc * 64 + row) * R + tr * 64 + cg * 8] = v;
  }
}

// ---------------- Hebbian W_fast update (in-place over corr region of d_out) ----------------
__global__ __launch_bounds__(256) void k_update(const float* __restrict__ corr, const float* __restrict__ wf,
                                                const float* __restrict__ eff, const float* __restrict__ sc,
                                                float* __restrict__ out_wf) {
  float xn = sc[0] * (1.0f / B_DIM) + 1e-6f;
  float inv = 1.0f / ((float)B_DIM * xn);
  bool on = (sc[1] * (1.0f / N_DIM)) > 0.001f;
  size_t i = ((size_t)blockIdx.x * 256 + threadIdx.x) * 4;
  int n = (int)(i >> 12);
  float lr = eff[n] * 0.015f;
  f4 c4 = *(const f4*)&corr[i];
  f4 w4 = *(const f4*)&wf[i];
  f4 r;
#pragma unroll
  for (int j = 0; j < 4; ++j) {
    float delta = fminf(fmaxf(c4[j] * inv - 0.2f * w4[j], -0.05f), 0.05f);
    r[j] = on ? (w4[j] + delta * lr) * 0.999f : w4[j];
  }
  *(f4*)&out_wf[i] = r;
}

extern "C" void kernel_launch(void* const* d_in, const int* in_sizes, int n_in,
                              void* d_out, int out_size, void* d_ws, size_t ws_size,
                              hipStream_t stream) {
  const float* x      = (const float*)d_in[0];
  const float* W_slow = (const float*)d_in[1];
  const float* W_fast = (const float*)d_in[2];
  const float* gamma  = (const float*)d_in[3];
  const float* beta   = (const float*)d_in[4];
  const float* w1     = (const float*)d_in[5];
  const float* b1     = (const float*)d_in[6];
  const float* w2     = (const float*)d_in[7];
  const float* b2     = (const float*)d_in[8];
  const float* gp     = (const float*)d_in[9];

  float* outF = (float*)d_out;                         // [8192][4096] out
  float* outW = (float*)d_out + (size_t)B_DIM * N_DIM; // [4096][4096] new_W_fast

  uint8_t* ws = (uint8_t*)d_ws;
  u16*  x_bf   = (u16*)(ws + 0);                        // 64MB
  u16*  outT   = (u16*)(ws + 0);                        // alias after x-transpose
  u16*  wsum   = (u16*)(ws + 67108864);                 // 32MB
  u16*  out_bf = (u16*)(ws + 67108864);                 // alias after GEMM1 (64MB)
  u16*  xT     = (u16*)(ws + 134217728);                // 64MB
  float* stats = (float*)(ws + 201326592);
  float* colsum   = stats;
  float* colsumsq = stats + 4096;
  float* xsumsq   = stats + 8192;
  float* effsum   = stats + 8193;
  float* eff      = stats + 8448;

  k_init<<<1, 256, 0, stream>>>(stats);
  k_prep_w<<<2048, 256, 0, stream>>>((const f4*)W_slow, (const f4*)W_fast, (u16x4*)wsum);
  k_prep_x<<<2048, 256, 0, stream>>>((const f4*)x, (u16x4*)x_bf, xsumsq);
  gemm8<<<dim3(N_DIM / 256, B_DIM / 256), 512, 0, stream>>>(x_bf, wsum, outF, B_DIM, N_DIM, K_DIM);
  k_colstats<<<dim3(N_DIM / 256, B_DIM / 128), 256, 0, stream>>>(outF, colsum, colsumsq);
  k_mlp<<<N_DIM / 256, 256, 0, stream>>>(colsum, colsumsq, w1, b1, w2, b2, gp, eff, effsum);
  k_ln<<<B_DIM, 256, 0, stream>>>(outF, gamma, beta, outF, out_bf);
  k_transpose<<<dim3(K_DIM / 64, B_DIM / 64), 256, 0, stream>>>(x_bf, xT, B_DIM, K_DIM);
  k_transpose<<<dim3(N_DIM / 64, B_DIM / 64), 256, 0, stream>>>(out_bf, outT, B_DIM, N_DIM);
  gemm8<<<dim3(K_DIM / 256, N_DIM / 256), 512, 0, stream>>>(outT, xT, outW, N_DIM, K_DIM, B_DIM);
  k_update<<<(N_DIM * K_DIM / 4) / 256, 256, 0, stream>>>(outW, W_fast, eff, xsumsq, outW);
}

// Round 7
// 758.319 us; speedup vs baseline: 2.6055x; 1.0167x over previous
//
#include <hip/hip_runtime.h>
#include <stdint.h>

#define B_DIM 8192
#define K_DIM 4096   // in_dim
#define N_DIM 4096   // out_dim

typedef unsigned short u16;
typedef float f4 __attribute__((ext_vector_type(4)));
typedef float f32x4 __attribute__((ext_vector_type(4)));
typedef __bf16 bf16x8 __attribute__((ext_vector_type(8)));
typedef unsigned short u16x8 __attribute__((ext_vector_type(8)));
typedef unsigned short u16x4 __attribute__((ext_vector_type(4)));

#define AS1(p) ((const __attribute__((address_space(1))) void*)(p))
#define AS3(p) ((__attribute__((address_space(3))) void*)(p))

__device__ __forceinline__ u16 f2bf(float f) {
  uint32_t u = __builtin_bit_cast(uint32_t, f);
  u += 0x7fffu + ((u >> 16) & 1u);   // RNE
  return (u16)(u >> 16);
}

__device__ __forceinline__ float wred(float v) {
#pragma unroll
  for (int o = 32; o > 0; o >>= 1) v += __shfl_xor(v, o);
  return v;
}

// ---------------- init: zero atomic accumulators ----------------
__global__ void k_init(float* __restrict__ stats) {
  for (int i = threadIdx.x; i < 8194; i += 256) stats[i] = 0.0f;
}

// ---------------- Wsum = bf16(W_slow + W_fast) ----------------
__global__ __launch_bounds__(256) void k_prep_w(const f4* __restrict__ wslow, const f4* __restrict__ wfast,
                                                u16x4* __restrict__ wo) {
  size_t stride = (size_t)gridDim.x * 256;
  size_t n4 = (size_t)N_DIM * K_DIM / 4;
  for (size_t i = (size_t)blockIdx.x * 256 + threadIdx.x; i < n4; i += stride) {
    f4 a = wslow[i], b = wfast[i];
    u16x4 o;
#pragma unroll
    for (int j = 0; j < 4; ++j) o[j] = f2bf(a[j] + b[j]);
    wo[i] = o;
  }
}

// ---------------- x -> bf16 (row-major AND transposed) + sum(x^2), fused ----------------
// 64x64 tiles: read x f32 once, write x_bf row-major + xT [k][b] via LDS.
__global__ __launch_bounds__(256) void k_prep_xT(const float* __restrict__ x, u16* __restrict__ xb,
                                                 u16* __restrict__ xT, float* __restrict__ xsumsq) {
  __shared__ u16 tile[64][68];   // stride 136B: 8B-aligned rows, decent transposed-read banks
  __shared__ float red[4];
  int tk = blockIdx.x, tb = blockIdx.y;
  int t = threadIdx.x;
  float s = 0.f;
#pragma unroll
  for (int q = 0; q < 4; ++q) {
    int idx = q * 256 + t;
    int row = idx >> 4, cg = idx & 15;           // 16 threads/row, f4 each
    f4 v = *(const f4*)&x[(size_t)(tb * 64 + row) * K_DIM + tk * 64 + cg * 4];
    u16x4 o;
#pragma unroll
    for (int j = 0; j < 4; ++j) { o[j] = f2bf(v[j]); s += v[j] * v[j]; }
    *(u16x4*)&xb[(size_t)(tb * 64 + row) * K_DIM + tk * 64 + cg * 4] = o;
    *(u16x4*)&tile[row][cg * 4] = o;
  }
  s = wred(s);
  if ((t & 63) == 0) red[t >> 6] = s;
  __syncthreads();
  if (t == 0) atomicAdd(xsumsq, red[0] + red[1] + red[2] + red[3]);
#pragma unroll
  for (int q = 0; q < 2; ++q) {
    int idx = q * 256 + t;
    int row = idx >> 3, cg = idx & 7;
    u16x8 v;
#pragma unroll
    for (int j = 0; j < 8; ++j) v[j] = tile[cg * 8 + j][row];
    *(u16x8*)&xT[(size_t)(tk * 64 + row) * B_DIM + tb * 64 + cg * 8] = v;
  }
}

// ============ 256x256-tile 8-phase bt-GEMM (R2-proven loop): C = A * B^T ============
// bf16 in, f32 out. BK=64, 512 threads = 8 waves (2M x 4N), wave tile 128x64.
// Fused epilogues: colsum/colsumsq atomics (GEMM1) or Hebbian W_fast update (GEMM2).
__global__ __launch_bounds__(512, 2) void gemm8(const u16* __restrict__ A, const u16* __restrict__ Bm,
                                                float* __restrict__ C, int M, int N, int K,
                                                float* __restrict__ colsum, float* __restrict__ colsumsq,
                                                const float* __restrict__ wfast, const float* __restrict__ eff,
                                                const float* __restrict__ sc) {
  __shared__ __align__(16) u16 As[32768];   // 2 bufs x 256 rows x 64 cols
  __shared__ __align__(16) u16 Bs[32768];

  const int tid = threadIdx.x, wave = tid >> 6, lane = tid & 63;
  const int li = lane & 15, hi = lane >> 4;
  const int wm = wave >> 2, wn = wave & 3;

  // bijective XCD swizzle (grid % 8 == 0 for both call sites)
  const int GX = N >> 8;
  const int nwg = GX * (M >> 8);
  int bid = blockIdx.y * GX + blockIdx.x;
  int swz = (bid & 7) * (nwg >> 3) + (bid >> 3);
  const int bx = swz % GX, by = swz / GX;
  const int m0 = by * 256, n0 = bx * 256;

  // per-lane staging source offsets (elements), swizzle-inverted:
  // LDS linear byte O holds tile byte T = O ^ (((O>>7)&7)<<4)
  int srcoff[2][2];
#pragma unroll
  for (int h = 0; h < 2; ++h)
#pragma unroll
    for (int q = 0; q < 2; ++q) {
      int O = h * 16384 + q * 8192 + wave * 1024 + lane * 16;
      int T = O ^ (((O >> 7) & 7) << 4);
      srcoff[h][q] = (T >> 7) * K + ((T & 127) >> 1);
    }

  const u16* Abase = A + (size_t)m0 * K;
  const u16* Bbase = Bm + (size_t)n0 * K;

#define STG_A(buf, h, kt) do { \
  __builtin_amdgcn_global_load_lds(AS1(Abase + (kt) + srcoff[h][0]), AS3(&As[(buf)*16384 + (h)*8192 + wave*512]), 16, 0, 0); \
  __builtin_amdgcn_global_load_lds(AS1(Abase + (kt) + srcoff[h][1]), AS3(&As[(buf)*16384 + (h)*8192 + 4096 + wave*512]), 16, 0, 0); \
} while (0)
#define STG_B(buf, h, kt) do { \
  __builtin_amdgcn_global_load_lds(AS1(Bbase + (kt) + srcoff[h][0]), AS3(&Bs[(buf)*16384 + (h)*8192 + wave*512]), 16, 0, 0); \
  __builtin_amdgcn_global_load_lds(AS1(Bbase + (kt) + srcoff[h][1]), AS3(&Bs[(buf)*16384 + (h)*8192 + 4096 + wave*512]), 16, 0, 0); \
} while (0)

  const int xa = (li & 7) << 3;                       // element-index XOR (byte bits[6:4])
  const int abase = (wm * 128 + li) * 64 + hi * 8;
  const int bbase = (wn * 64 + li) * 64 + hi * 8;
#define LDA_(dst, buf, m, ks) dst = *(const bf16x8*)&As[(buf)*16384 + (((abase + (m)*1024 + (ks)*32)) ^ xa)]
#define LDB_(dst, buf, n, ks) dst = *(const bf16x8*)&Bs[(buf)*16384 + (((bbase + (n)*1024 + (ks)*32)) ^ xa)]

  f32x4 acc[8][4] = {};
  bf16x8 a[8][2], b[4][2];
  const int NT = K >> 6;

  // prologue: tile0 {A0,A1,B0,B1} -> buf0 ; tile1 {A0,A1,B0} -> buf1
  STG_A(0, 0, 0); STG_A(0, 1, 0); STG_B(0, 0, 0); STG_B(0, 1, 0);
  STG_A(1, 0, 64); STG_A(1, 1, 64); STG_B(1, 0, 64);
  asm volatile("s_waitcnt vmcnt(6)" ::: "memory");
  __builtin_amdgcn_s_barrier();

  for (int t = 0; t < NT; ++t) {
    const int buf = t & 1;
    const int ktn = (t + 1) << 6, ktnn = (t + 2) << 6;

    // ---- P0: read a[0..3], b[0..1]; stage B1(t+1) -> buf^1 ----
#pragma unroll
    for (int m = 0; m < 4; ++m) { LDA_(a[m][0], buf, m, 0); LDA_(a[m][1], buf, m, 1); }
#pragma unroll
    for (int n = 0; n < 2; ++n) { LDB_(b[n][0], buf, n, 0); LDB_(b[n][1], buf, n, 1); }
    if (t + 1 < NT) STG_B(buf ^ 1, 1, ktn);
    __builtin_amdgcn_s_barrier();
    asm volatile("s_waitcnt lgkmcnt(0)" ::: "memory");
    __builtin_amdgcn_sched_barrier(0);
    __builtin_amdgcn_s_setprio(1);
#pragma unroll
    for (int ks = 0; ks < 2; ++ks)
#pragma unroll
      for (int m = 0; m < 4; ++m)
#pragma unroll
        for (int n = 0; n < 2; ++n)
          acc[m][n] = __builtin_amdgcn_mfma_f32_16x16x32_bf16(a[m][ks], b[n][ks], acc[m][n], 0, 0, 0);
    __builtin_amdgcn_s_setprio(0);
    __builtin_amdgcn_s_barrier();

    // ---- P1: read a[4..7] ----
#pragma unroll
    for (int m = 4; m < 8; ++m) { LDA_(a[m][0], buf, m, 0); LDA_(a[m][1], buf, m, 1); }
    __builtin_amdgcn_s_barrier();
    asm volatile("s_waitcnt lgkmcnt(0)" ::: "memory");
    __builtin_amdgcn_sched_barrier(0);
    __builtin_amdgcn_s_setprio(1);
#pragma unroll
    for (int ks = 0; ks < 2; ++ks)
#pragma unroll
      for (int m = 4; m < 8; ++m)
#pragma unroll
        for (int n = 0; n < 2; ++n)
          acc[m][n] = __builtin_amdgcn_mfma_f32_16x16x32_bf16(a[m][ks], b[n][ks], acc[m][n], 0, 0, 0);
    __builtin_amdgcn_s_setprio(0);
    __builtin_amdgcn_s_barrier();

    // ---- P2: read b[2..3]; stage A0,A1(t+2) -> buf (reads of A done @P1) ----
#pragma unroll
    for (int n = 2; n < 4; ++n) { LDB_(b[n][0], buf, n, 0); LDB_(b[n][1], buf, n, 1); }
    if (t + 2 < NT) { STG_A(buf, 0, ktnn); STG_A(buf, 1, ktnn); }
    __builtin_amdgcn_s_barrier();
    asm volatile("s_waitcnt lgkmcnt(0)" ::: "memory");
    __builtin_amdgcn_sched_barrier(0);
    __builtin_amdgcn_s_setprio(1);
#pragma unroll
    for (int ks = 0; ks < 2; ++ks)
#pragma unroll
      for (int m = 0; m < 4; ++m)
#pragma unroll
        for (int n = 2; n < 4; ++n)
          acc[m][n] = __builtin_amdgcn_mfma_f32_16x16x32_bf16(a[m][ks], b[n][ks], acc[m][n], 0, 0, 0);
    __builtin_amdgcn_s_setprio(0);
    __builtin_amdgcn_s_barrier();

    // ---- P3: stage B0(t+2) -> buf (reads of B-half0 done @P2); boundary vmcnt ----
    if (t + 2 < NT) STG_B(buf, 0, ktnn);
    __builtin_amdgcn_s_barrier();
    __builtin_amdgcn_s_setprio(1);
#pragma unroll
    for (int ks = 0; ks < 2; ++ks)
#pragma unroll
      for (int m = 4; m < 8; ++m)
#pragma unroll
        for (int n = 2; n < 4; ++n)
          acc[m][n] = __builtin_amdgcn_mfma_f32_16x16x32_bf16(a[m][ks], b[n][ks], acc[m][n], 0, 0, 0);
    __builtin_amdgcn_s_setprio(0);
    if (t + 1 < NT) {
      if (t + 2 < NT) asm volatile("s_waitcnt vmcnt(6)" ::: "memory");
      else            asm volatile("s_waitcnt vmcnt(0)" ::: "memory");
    }
    __builtin_amdgcn_s_barrier();
  }

  // epilogue: C/D layout col = lane&15, row = (lane>>4)*4 + j
  if (wfast) {
    // Hebbian update fused (GEMM2): acc holds raw corr = out^T @ x
    float xn = sc[0] * (1.0f / 8192.0f) + 1e-6f;   // sum(x^2)/B + eps
    float inv = 1.0f / (8192.0f * xn);             // raw -> correlation/x_norm
    bool on = (sc[1] * (1.0f / 4096.0f)) > 0.001f; // eff.mean() > 0.001
    const int colb = n0 + wn * 64 + li;
    const int rowb = m0 + wm * 128 + hi * 4;
#pragma unroll
    for (int m = 0; m < 8; ++m) {
      f4 e4 = *(const f4*)&eff[rowb + m * 16];
#pragma unroll
      for (int j = 0; j < 4; ++j) {
        float lr = e4[j] * 0.015f;
        const size_t ro = (size_t)(rowb + m * 16 + j) * N;
#pragma unroll
        for (int n = 0; n < 4; ++n) {
          float w = wfast[ro + colb + n * 16];
          float delta = fminf(fmaxf(acc[m][n][j] * inv - 0.2f * w, -0.05f), 0.05f);
          C[ro + colb + n * 16] = on ? (w + delta * lr) * 0.999f : w;
        }
      }
    }
  } else {
    float* Cp = C + (size_t)(m0 + wm * 128 + hi * 4) * N + n0 + wn * 64 + li;
#pragma unroll
    for (int m = 0; m < 8; ++m)
#pragma unroll
      for (int n = 0; n < 4; ++n)
#pragma unroll
        for (int j = 0; j < 4; ++j)
          Cp[(size_t)(m * 16 + j) * N + n * 16] = acc[m][n][j];
    if (colsum) {
      // column batch-stats fused (GEMM1): wave covers 128 rows; both wm waves add
#pragma unroll
      for (int n = 0; n < 4; ++n) {
        float s = 0.f, q = 0.f;
#pragma unroll
        for (int m = 0; m < 8; ++m)
#pragma unroll
          for (int j = 0; j < 4; ++j) { float v = acc[m][n][j]; s += v; q += v * v; }
        s += __shfl_xor(s, 16); s += __shfl_xor(s, 32);
        q += __shfl_xor(q, 16); q += __shfl_xor(q, 32);
        if (hi == 0) {
          int col = n0 + wn * 64 + n * 16 + li;
          atomicAdd(&colsum[col], s);
          atomicAdd(&colsumsq[col], q);
        }
      }
    }
  }
#undef STG_A
#undef STG_B
#undef LDA_
#undef LDB_
}

// ---------------- plasticity MLP per column ----------------
__global__ __launch_bounds__(256) void k_mlp(const float* __restrict__ colsum, const float* __restrict__ colsumsq,
                                             const float* __restrict__ w1, const float* __restrict__ b1,
                                             const float* __restrict__ w2, const float* __restrict__ b2,
                                             const float* __restrict__ gp, float* __restrict__ eff,
                                             float* __restrict__ effsum) {
  __shared__ float red[4];
  int c = blockIdx.x * 256 + threadIdx.x;
  float mean = colsum[c] * (1.0f / B_DIM);
  float var = (colsumsq[c] - (float)B_DIM * mean * mean) * (1.0f / (B_DIM - 1));
  float sd = sqrtf(fmaxf(var, 0.f)) + 1e-6f;
  float acc = b2[0];
#pragma unroll
  for (int i = 0; i < 16; ++i) {
    float h = tanhf(mean * w1[2 * i] + sd * w1[2 * i + 1] + b1[i]);
    acc += h * w2[i];
  }
  float p = 1.0f / (1.0f + expf(-acc));
  float e = gp[0] * p;          // * (1 - PRED_ERR), PRED_ERR = 0
  eff[c] = e;
  float s = wred(e);
  int lane = threadIdx.x & 63, wave = threadIdx.x >> 6;
  if (lane == 0) red[wave] = s;
  __syncthreads();
  if (threadIdx.x == 0) atomicAdd(effsum, red[0] + red[1] + red[2] + red[3]);
}

// ---------------- row LayerNorm + 5*tanh(/5); in-place over pre_act; also bf16 copy ----------------
__global__ __launch_bounds__(256) void k_ln(const float* __restrict__ pre, const float* __restrict__ gamma,
                                            const float* __restrict__ beta, float* __restrict__ outF,
                                            u16* __restrict__ outB) {
  __shared__ float row[N_DIM];
  __shared__ float red[2][4];
  int t = threadIdx.x, lane = t & 63, wave = t >> 6;
  const float* p = pre + (size_t)blockIdx.x * N_DIM;
  float s = 0.f;
#pragma unroll
  for (int q = 0; q < 4; ++q) {
    int c = (q * 256 + t) * 4;
    f4 v = *(const f4*)&p[c];
    *(f4*)&row[c] = v;
    s += v[0] + v[1] + v[2] + v[3];
  }
  s = wred(s);
  if (lane == 0) red[0][wave] = s;
  __syncthreads();
  float mean = (red[0][0] + red[0][1] + red[0][2] + red[0][3]) * (1.0f / N_DIM);
  float vs = 0.f;
#pragma unroll
  for (int q = 0; q < 4; ++q) {
    int c = (q * 256 + t) * 4;
    f4 v = *(const f4*)&row[c];
#pragma unroll
    for (int j = 0; j < 4; ++j) { float d = v[j] - mean; vs += d * d; }
  }
  vs = wred(vs);
  if (lane == 0) red[1][wave] = vs;
  __syncthreads();
  float var = (red[1][0] + red[1][1] + red[1][2] + red[1][3]) * (1.0f / N_DIM);
  float rstd = rsqrtf(var + 1e-5f);
  float* o = outF + (size_t)blockIdx.x * N_DIM;
  u16* ob = outB + (size_t)blockIdx.x * N_DIM;
#pragma unroll
  for (int q = 0; q < 4; ++q) {
    int c = (q * 256 + t) * 4;
    f4 v = *(const f4*)&row[c];
    f4 g = *(const f4*)&gamma[c];
    f4 be = *(const f4*)&beta[c];
    f4 r;
    u16x4 rb;
#pragma unroll
    for (int j = 0; j < 4; ++j) {
      float ln = (v[j] - mean) * rstd * g[j] + be[j];
      float ov = 5.0f * tanhf(ln * 0.2f);
      r[j] = ov; rb[j] = f2bf(ov);
    }
    *(f4*)&o[c] = r;
    *(u16x4*)&ob[c] = rb;
  }
}

// ---------------- bf16 64x64 tile transpose: dst[c][r] = src[r][c] ----------------
__global__ __launch_bounds__(256) void k_transpose(const u16* __restrict__ src, u16* __restrict__ dst,
                                                   int R, int C) {
  __shared__ u16 tile[64][65];
  int tc = blockIdx.x, tr = blockIdx.y;
  int t = threadIdx.x;
#pragma unroll
  for (int q = 0; q < 2; ++q) {
    int idx = q * 256 + t;
    int row = idx >> 3, cg = idx & 7;
    u16x8 v = *(const u16x8*)&src[(size_t)(tr * 64 + row) * C + tc * 64 + cg * 8];
#pragma unroll
    for (int j = 0; j < 8; ++j) tile[row][cg * 8 + j] = v[j];
  }
  __syncthreads();
#pragma unroll
  for (int q = 0; q < 2; ++q) {
    int idx = q * 256 + t;
    int row = idx >> 3, cg = idx & 7;
    u16x8 v;
#pragma unroll
    for (int j = 0; j < 8; ++j) v[j] = tile[cg * 8 + j][row];
    *(u16x8*)&dst[(size_t)(tc * 64 + row) * R + tr * 64 + cg * 8] = v;
  }
}

extern "C" void kernel_launch(void* const* d_in, const int* in_sizes, int n_in,
                              void* d_out, int out_size, void* d_ws, size_t ws_size,
                              hipStream_t stream) {
  const float* x      = (const float*)d_in[0];
  const float* W_slow = (const float*)d_in[1];
  const float* W_fast = (const float*)d_in[2];
  const float* gamma  = (const float*)d_in[3];
  const float* beta   = (const float*)d_in[4];
  const float* w1     = (const float*)d_in[5];
  const float* b1     = (const float*)d_in[6];
  const float* w2     = (const float*)d_in[7];
  const float* b2     = (const float*)d_in[8];
  const float* gp     = (const float*)d_in[9];

  float* outF = (float*)d_out;                         // [8192][4096] out
  float* outW = (float*)d_out + (size_t)B_DIM * N_DIM; // [4096][4096] new_W_fast

  uint8_t* ws = (uint8_t*)d_ws;
  u16*  x_bf   = (u16*)(ws + 0);                        // 64MB
  u16*  outT   = (u16*)(ws + 0);                        // alias after GEMM1 done with x_bf
  u16*  wsum   = (u16*)(ws + 67108864);                 // 32MB
  u16*  out_bf = (u16*)(ws + 67108864);                 // alias after GEMM1 (64MB)
  u16*  xT     = (u16*)(ws + 134217728);                // 64MB (written early, lives to GEMM2)
  float* stats = (float*)(ws + 201326592);
  float* colsum   = stats;
  float* colsumsq = stats + 4096;
  float* xsumsq   = stats + 8192;   // sc[0]
  float* effsum   = stats + 8193;   // sc[1]
  float* eff      = stats + 8448;

  k_init<<<1, 256, 0, stream>>>(stats);
  k_prep_w<<<2048, 256, 0, stream>>>((const f4*)W_slow, (const f4*)W_fast, (u16x4*)wsum);
  k_prep_xT<<<dim3(K_DIM / 64, B_DIM / 64), 256, 0, stream>>>(x, x_bf, xT, xsumsq);
  gemm8<<<dim3(N_DIM / 256, B_DIM / 256), 512, 0, stream>>>(x_bf, wsum, outF, B_DIM, N_DIM, K_DIM,
                                                            colsum, colsumsq, nullptr, nullptr, nullptr);
  k_mlp<<<N_DIM / 256, 256, 0, stream>>>(colsum, colsumsq, w1, b1, w2, b2, gp, eff, effsum);
  k_ln<<<B_DIM, 256, 0, stream>>>(outF, gamma, beta, outF, out_bf);
  k_transpose<<<dim3(N_DIM / 64, B_DIM / 64), 256, 0, stream>>>(out_bf, outT, B_DIM, N_DIM);
  gemm8<<<dim3(K_DIM / 256, N_DIM / 256), 512, 0, stream>>>(outT, xT, outW, N_DIM, K_DIM, B_DIM,
                                                            nullptr, nullptr, W_fast, eff, xsumsq);
}